// Round 9
// baseline (358.252 us; speedup 1.0000x reference)
//
#include <hip/hip_runtime.h>

#define N_NODES 50000
#define N_EDGES 600000
#define N_GRAPHS 2048
#define EMB 128
#define TDIM 384
#define TS_LD 392               // padded LDS row stride (shorts): 2-way bank alias only
#define HN (N_NODES * EMB)
#define GROWS 64                // k_gemm rows per block

// bucket-sort CSR build (atomic-free; replaces hist+scan+scatter)
#define EPB 2048                               // edges per count/scatter block
#define NBLKA ((N_EDGES + EPB - 1) / EPB)      // 293
#define NCOARSE ((N_NODES + 255) / 256)        // 196 coarse buckets (dst>>8)

// merged-prepass block ranges (384 threads/block)
#define PRE_ATOM_NB 8334        // 6 nodes/block, FULL wave per node (async LDS gathers)
#define PRE_WCONV_NB 384        // one (layer,col) per block
#define PRE_GB_NB 131           // ceil(50000/384)

typedef __attribute__((ext_vector_type(8))) short bf16x8;
typedef __attribute__((ext_vector_type(4))) float f32x4;
#define MFMA_BF16(a, b, c) __builtin_amdgcn_mfma_f32_16x16x32_bf16(a, b, c, 0, 0, 0)

#define AS1 __attribute__((address_space(1)))
#define AS3 __attribute__((address_space(3)))
__device__ inline void gl_lds16(const void* g, void* l) {
  // async global->LDS, 16B/lane: LDS dest = l + lane*16 (wave-uniform base), no dest VGPRs
  __builtin_amdgcn_global_load_lds((const AS1 void*)g, (AS3 void*)l, 16, 0, 0);
}

__device__ inline unsigned short f2bf(float f) {
  unsigned int u = __float_as_uint(f);
  u += 0x7fffu + ((u >> 16) & 1u);   // round to nearest even
  return (unsigned short)(u >> 16);
}
__device__ inline float bf2f(unsigned short b) {
  return __uint_as_float(((unsigned int)b) << 16);
}
__device__ inline bf16x8 pack8(float4 lo, float4 hi) {
  bf16x8 r;
  r[0] = (short)f2bf(lo.x); r[1] = (short)f2bf(lo.y);
  r[2] = (short)f2bf(lo.z); r[3] = (short)f2bf(lo.w);
  r[4] = (short)f2bf(hi.x); r[5] = (short)f2bf(hi.y);
  r[6] = (short)f2bf(hi.z); r[7] = (short)f2bf(hi.w);
  return r;
}

// ---------------- merged prepass: atom-encoder | W-transpose | graph-bounds ----------------
// Hist REMOVED (rounds 0-8: every global-atomic hist variant pinned at 43-52us ~= the
// ~14 G atomics/s device ceiling). CSR build now atomic-free via bucket sort below.
__global__ __launch_bounds__(384) void k_pre(const int* __restrict__ x,
                                             const float* __restrict__ atom_emb,
                                             unsigned short* __restrict__ h_bf,
                                             const float* __restrict__ W,
                                             unsigned short* __restrict__ wt,
                                             const int* __restrict__ batch,
                                             int* __restrict__ gs) {
  __shared__ float sb[6 * 1280];   // 30 KB: 6 waves x (9 rows of 128f + scratch tail)
  int blk = blockIdx.x;
  if (blk < PRE_ATOM_NB) {
    const int wv = threadIdx.x >> 6;
    const int lane = threadIdx.x & 63;
    int n = blk * 6 + wv;
    if (n < N_NODES) {
      const int nu = __builtin_amdgcn_readfirstlane(n);
      const int* xr = x + nu * 9;
      int ix[9];
#pragma unroll
      for (int c = 0; c < 9; ++c) ix[c] = xr[c];   // wave-uniform -> s_loads
      float* wbase = sb + wv * 1280;
      const int half = lane >> 5;       // 0: lanes 0-31, 1: lanes 32-63
      const int sub16 = lane & 31;      // 16B slot within the row
#pragma unroll
      for (int j = 0; j < 4; ++j) {
        int c = 2 * j + half;
        const float* g = atom_emb + (size_t)(c * 100 + ix[c]) * EMB + sub16 * 4;
        gl_lds16(g, wbase + j * 256);   // row 2j -> +j*1024B, row 2j+1 -> +j*1024B+512B
      }
      {  // row 8: both halves load the same 512B (lanes 32-63 land in scratch tail)
        const float* g = atom_emb + (size_t)(8 * 100 + ix[8]) * EMB + sub16 * 4;
        gl_lds16(g, wbase + 1024);
      }
      asm volatile("s_waitcnt vmcnt(0)" ::: "memory");
      float2 acc = {0.f, 0.f};
#pragma unroll
      for (int c = 0; c < 9; ++c) {     // row c at wbase + c*128 floats
        float2 v = *(const float2*)(wbase + c * 128 + lane * 2);
        acc.x += v.x; acc.y += v.y;
      }
      *(ushort2*)(h_bf + (size_t)nu * EMB + lane * 2) = ushort2{f2bf(acc.x), f2bf(acc.y)};
    }
    return;
  }
  blk -= PRE_ATOM_NB;
  if (blk < PRE_WCONV_NB) {
    int layer = blk >> 7, c = blk & 127, k = threadIdx.x;
    float v = W[(((layer * 3 + (k >> 7)) * 128) + (k & 127)) * 128 + c];
    wt[(size_t)blk * 384 + k] = f2bf(v);
    return;
  }
  blk -= PRE_WCONV_NB;
  {
    int i = blk * 384 + threadIdx.x;
    if (i < N_NODES) {
      int b = batch[i];
      int bp = (i == 0) ? -1 : batch[i - 1];
      for (int g = bp + 1; g <= b; ++g) gs[g] = i;
      if (i == N_NODES - 1) {
        for (int g = b + 1; g <= N_GRAPHS; ++g) gs[g] = N_NODES;
      }
    }
  }
}

// ---------------- bucket-sort CSR build (no global atomics) ----------------
// Pass A: per-block LDS hist of coarse digit dst>>8.
__global__ __launch_bounds__(256) void k_cnt(const int* __restrict__ ei,
                                             int* __restrict__ ghist) {
  __shared__ int h[256];
  const int t = threadIdx.x;
  h[t] = 0;
  __syncthreads();
  const int base = blockIdx.x * EPB;
#pragma unroll
  for (int k = 0; k < 8; ++k) {
    int e = base + k * 256 + t;
    if (e < N_EDGES) atomicAdd(&h[ei[N_EDGES + e] >> 8], 1);   // LDS atomic
  }
  __syncthreads();
  if (t < NCOARSE) ghist[(size_t)t * NBLKA + blockIdx.x] = h[t];
}

// Pass B: serial per-digit scan over blocks + cross-digit scan -> bucket_base.
__global__ __launch_bounds__(256) void k_sscan(int* __restrict__ ghist,
                                               int* __restrict__ bucket_base,
                                               int* __restrict__ row_start) {
  __shared__ int s[256];
  const int t = threadIdx.x;
  int sum = 0;
  if (t < NCOARSE) {
    int* row = ghist + (size_t)t * NBLKA;
    for (int b = 0; b < NBLKA; ++b) { int v = row[b]; row[b] = sum; sum += v; }
  }
  s[t] = sum;
  __syncthreads();
  for (int off = 1; off < 256; off <<= 1) {
    int v = (t >= off) ? s[t - off] : 0;
    __syncthreads();
    s[t] += v;
    __syncthreads();
  }
  if (t < NCOARSE) bucket_base[t] = s[t] - sum;   // exclusive
  if (t == 0) { bucket_base[NCOARSE] = N_EDGES; row_start[N_NODES] = N_EDGES; }
}

// Pass C: scatter edges into coarse-bucket order; payload packed {dst|eap<<16, src}.
__global__ __launch_bounds__(256) void k_coarse(const int* __restrict__ ei,
                                                const int* __restrict__ ea,
                                                const int* __restrict__ ghist,
                                                const int* __restrict__ bucket_base,
                                                int2* __restrict__ tmp) {
  __shared__ int cnt[256];
  const int t = threadIdx.x;
  cnt[t] = 0;
  __syncthreads();
  const int base = blockIdx.x * EPB;
#pragma unroll
  for (int k = 0; k < 8; ++k) {
    int e = base + k * 256 + t;
    if (e < N_EDGES) {
      int dst = ei[N_EDGES + e];
      int d = dst >> 8;
      int r = atomicAdd(&cnt[d], 1);   // LDS atomic: block-local rank in bucket
      int pos = bucket_base[d] + ghist[(size_t)d * NBLKA + blockIdx.x] + r;
      int eap = ea[e * 3 + 0] | (ea[e * 3 + 1] << 3) | (ea[e * 3 + 2] << 6);
      tmp[pos] = int2{dst | (eap << 16), ei[e]};
    }
  }
}

// Pass D: one block per coarse bucket -- fine hist (dst&255), LDS scan writes
// row_start DIRECTLY, then scatter into final sorted_se {src, eap}.
__global__ __launch_bounds__(256) void k_fine(const int2* __restrict__ tmp,
                                              const int* __restrict__ bucket_base,
                                              int* __restrict__ row_start,
                                              int2* __restrict__ sorted_se) {
  __shared__ int h[256];
  __shared__ int s[256];
  __shared__ int ex[256];
  const int t = threadIdx.x;
  const int d = blockIdx.x;
  const int b0 = bucket_base[d], b1 = bucket_base[d + 1];
  h[t] = 0;
  __syncthreads();
  for (int i = b0 + t; i < b1; i += 256) atomicAdd(&h[tmp[i].x & 255], 1);
  __syncthreads();
  s[t] = h[t];
  __syncthreads();
  for (int off = 1; off < 256; off <<= 1) {
    int v = (t >= off) ? s[t - off] : 0;
    __syncthreads();
    s[t] += v;
    __syncthreads();
  }
  ex[t] = s[t] - h[t];                 // exclusive offsets within bucket
  int node = d * 256 + t;
  if (node < N_NODES) row_start[node] = b0 + ex[t];
  h[t] = 0;
  __syncthreads();
  for (int i = b0 + t; i < b1; i += 256) {
    int2 r = tmp[i];
    int f = r.x & 255;
    int pos = b0 + ex[f] + atomicAdd(&h[f], 1);   // LDS atomic
    sorted_se[pos] = int2{r.y, (r.x >> 16) & 511};
  }
}

// ---------------- Edge aggregation: QUARTER-WAVE per node, unroll-8 (round-5 local optimum) --------
// Ledger: bucketing (r6) -8us, unroll-16 (r7) -27us, half-wave (r0) -7us -- all reverted.
// 16 lanes x bf16x8 = full 256B row per gather; 4 nodes x 8 edges = 8 KB in flight/wave.
__global__ __launch_bounds__(256) void k_agg(const int2* __restrict__ sorted_se,
                                             const int* __restrict__ row_start,
                                             const float* __restrict__ bl,  // bond_emb[layer]: [3][8][3]
                                             const unsigned short* __restrict__ h_bf,
                                             unsigned short* __restrict__ t_bf) {
  __shared__ float4 combo[512];  // 8 KB
  for (int c = threadIdx.x; c < 512; c += 256) {
    int a0 = c & 7, a1 = (c >> 3) & 7, a2 = (c >> 6) & 7;
    combo[c] = float4{bl[a0 * 3 + 0] + bl[24 + a1 * 3 + 0] + bl[48 + a2 * 3 + 0],
                      bl[a0 * 3 + 1] + bl[24 + a1 * 3 + 1] + bl[48 + a2 * 3 + 1],
                      bl[a0 * 3 + 2] + bl[24 + a1 * 3 + 2] + bl[48 + a2 * 3 + 2], 0.f};
  }
  __syncthreads();
  const int node = blockIdx.x * 16 + (threadIdx.x >> 4);  // quarter-wave per node
  const int sub = threadIdx.x & 15;                       // cols sub*8..+7
  const int beg = row_start[node], end = row_start[node + 1];
  float4 l0 = {0.f, 0.f, 0.f, 0.f}, h0 = l0;   // channel 0: cols lo/hi
  float4 l1 = l0, h1 = l0;                     // channel 1
  float4 l2 = l0, h2 = l0;                     // channel 2
  int e = beg;
  const int full_end = beg + ((end - beg) & ~7);
  for (; e < full_end; e += 8) {           // fast path: no bounds logic
    int2 se[8];
#pragma unroll
    for (int j = 0; j < 8; ++j) se[j] = sorted_se[e + j];
    bf16x8 u[8];
#pragma unroll
    for (int j = 0; j < 8; ++j)
      u[j] = *(const bf16x8*)(h_bf + (size_t)se[j].x * EMB + sub * 8);
#pragma unroll
    for (int j = 0; j < 8; ++j) {
      float4 w = combo[se[j].y];
      float4 vlo = {bf2f((unsigned short)u[j][0]), bf2f((unsigned short)u[j][1]),
                    bf2f((unsigned short)u[j][2]), bf2f((unsigned short)u[j][3])};
      float4 vhi = {bf2f((unsigned short)u[j][4]), bf2f((unsigned short)u[j][5]),
                    bf2f((unsigned short)u[j][6]), bf2f((unsigned short)u[j][7])};
      l0 += vlo * w.x; h0 += vhi * w.x;
      l1 += vlo * w.y; h1 += vhi * w.y;
      l2 += vlo * w.z; h2 += vhi * w.z;
    }
  }
  if (e < end) {                           // tail chunk: clamped + weight-selected
    int2 se[8];
#pragma unroll
    for (int j = 0; j < 8; ++j) {
      int idx = e + j;
      se[j] = sorted_se[idx < end ? idx : end - 1];
    }
    bf16x8 u[8];
#pragma unroll
    for (int j = 0; j < 8; ++j)
      u[j] = *(const bf16x8*)(h_bf + (size_t)se[j].x * EMB + sub * 8);
#pragma unroll
    for (int j = 0; j < 8; ++j) {
      float4 w = (e + j < end) ? combo[se[j].y] : float4{0.f, 0.f, 0.f, 0.f};
      float4 vlo = {bf2f((unsigned short)u[j][0]), bf2f((unsigned short)u[j][1]),
                    bf2f((unsigned short)u[j][2]), bf2f((unsigned short)u[j][3])};
      float4 vhi = {bf2f((unsigned short)u[j][4]), bf2f((unsigned short)u[j][5]),
                    bf2f((unsigned short)u[j][6]), bf2f((unsigned short)u[j][7])};
      l0 += vlo * w.x; h0 += vhi * w.x;
      l1 += vlo * w.y; h1 += vhi * w.y;
      l2 += vlo * w.z; h2 += vhi * w.z;
    }
  }
  size_t base = (size_t)node * TDIM + sub * 8;
  *(bf16x8*)(t_bf + base)       = pack8(l0, h0);
  *(bf16x8*)(t_bf + base + 128) = pack8(l1, h1);
  *(bf16x8*)(t_bf + base + 256) = pack8(l2, h2);
}

// ---------------- MFMA GEMM: 64-row blocks (halved L2 weight re-fetch) ----------------
// Block 512 thr = 8 waves; 64 nodes/block; grid 782; LDS 50 KB -> 3 blocks/CU (24 waves).
// Wave wv owns cols wv*16..+15: 12 resident B-frags amortized over 4 row-tiles x 12
// MFMAs = 48 MFMAs. A-frag: A[m=lane&15][k=(lane>>4)*8+j]; B-frag: B[k][n=lane&15];
// C/D: col=lane&15, row=(lane>>4)*4+reg.
__global__ __launch_bounds__(512) void k_gemm(const unsigned short* __restrict__ t_bf,
                                              const unsigned short* __restrict__ wt,  // [128][384]
                                              const float* __restrict__ bl,  // [3][128]
                                              const unsigned short* __restrict__ h_in_bf,
                                              unsigned short* __restrict__ h_out_bf,
                                              int do_relu) {
  __shared__ unsigned short ts[GROWS * TS_LD];   // 50.2 KB
  const int nb = blockIdx.x * GROWS;
  for (int i = threadIdx.x; i < GROWS * 48; i += 512) {
    int r = i / 48, cc = i % 48;
    bf16x8 v = {};
    int row = nb + r;
    if (row < N_NODES) v = *(const bf16x8*)(t_bf + (size_t)row * TDIM + cc * 8);
    *(bf16x8*)(ts + r * TS_LD + cc * 8) = v;
  }
  __syncthreads();

  const int wv = threadIdx.x >> 6;
  const int lane = threadIdx.x & 63;
  const int m = lane & 15;
  const int kq = lane >> 4;
  const int c = wv * 16 + m;

  const unsigned short* pB = wt + (size_t)c * TDIM + kq * 8;
  bf16x8 B[12];
#pragma unroll
  for (int kc = 0; kc < 12; ++kc) B[kc] = *(const bf16x8*)(pB + kc * 32);

  const float bias = bl[c] + bl[128 + c] + bl[256 + c];

#pragma unroll
  for (int rt = 0; rt < 4; ++rt) {
    const unsigned short* pA = ts + (rt * 16 + m) * TS_LD + kq * 8;
    bf16x8 A[12];
#pragma unroll
    for (int kc = 0; kc < 12; ++kc) A[kc] = *(const bf16x8*)(pA + kc * 32);
    f32x4 acc = {0.f, 0.f, 0.f, 0.f};
#pragma unroll
    for (int kc = 0; kc < 12; ++kc) acc = MFMA_BF16(A[kc], B[kc], acc);
#pragma unroll
    for (int r = 0; r < 4; ++r) {
      int row = nb + rt * 16 + kq * 4 + r;
      if (row < N_NODES) {
        size_t idx = (size_t)row * EMB + c;
        float v = acc[r] + bias;
        if (do_relu) v = fmaxf(v, 0.f);
        float hn = bf2f(h_in_bf[idx]) + v;
        h_out_bf[idx] = f2bf(hn);
      }
    }
  }
}

// ---------------- fused mean-pool + head: block g reduces its contiguous node range ----------------
__global__ __launch_bounds__(128) void k_head(const unsigned short* __restrict__ h_bf,
                                              const int* __restrict__ gs,
                                              const float* __restrict__ fc1_w,
                                              const float* __restrict__ fc1_b,
                                              const float* __restrict__ fc2_w,
                                              const float* __restrict__ fc2_b,
                                              float* __restrict__ out) {
  __shared__ float hg[EMB];
  __shared__ float red[EMB];
  int g = blockIdx.x, e = threadIdx.x;
  int ns = gs[g], ne = gs[g + 1];
  float acc = 0.f;
  for (int n = ns; n < ne; ++n) acc += bf2f(h_bf[(size_t)n * EMB + e]);
  float cnt = fmaxf((float)(ne - ns), 1.f);
  hg[e] = acc / cnt;
  __syncthreads();
  float a2 = fc1_b[e];
  for (int j = 0; j < EMB; ++j) a2 += hg[j] * fc1_w[j * EMB + e];
  red[e] = a2 * fc2_w[e];
  __syncthreads();
  for (int s = 64; s > 0; s >>= 1) {
    if (e < s) red[e] += red[e + s];
    __syncthreads();
  }
  if (e == 0) out[g] = red[0] + fc2_b[0];
}

extern "C" void kernel_launch(void* const* d_in, const int* in_sizes, int n_in,
                              void* d_out, int out_size, void* d_ws, size_t ws_size,
                              hipStream_t stream) {
  const int*   x        = (const int*)d_in[0];
  const int*   ei       = (const int*)d_in[1];
  const int*   ea       = (const int*)d_in[2];
  const int*   batch    = (const int*)d_in[3];
  const float* atom_emb = (const float*)d_in[4];
  const float* bond_emb = (const float*)d_in[5];
  const float* W        = (const float*)d_in[6];
  const float* b        = (const float*)d_in[7];
  const float* fc1_w    = (const float*)d_in[8];
  const float* fc1_b    = (const float*)d_in[9];
  const float* fc2_w    = (const float*)d_in[10];
  const float* fc2_b    = (const float*)d_in[11];
  float* out = (float*)d_out;

  char* p = (char*)d_ws;
  auto alloc = [&](size_t bytes) { char* r = p; p += (bytes + 255) & ~(size_t)255; return r; };
  unsigned short* h0_bf      = (unsigned short*)alloc((size_t)HN * 2);
  unsigned short* h1_bf      = (unsigned short*)alloc((size_t)HN * 2);
  unsigned short* t_bf       = (unsigned short*)alloc((size_t)N_NODES * TDIM * 2);
  unsigned short* wt         = (unsigned short*)alloc((size_t)3 * 128 * TDIM * 2);
  int*            gs         = (int*)alloc((size_t)(N_GRAPHS + 1) * 4);
  int*            row_start  = (int*)alloc((size_t)(N_NODES + 1) * 4);
  int*            ghist      = (int*)alloc((size_t)NCOARSE * NBLKA * 4);   // ~230 KB
  int*            bucket_base= (int*)alloc((size_t)(NCOARSE + 1) * 4);
  int2*           tmp_se     = (int2*)alloc((size_t)N_EDGES * 8);          // 4.8 MB
  int2*           sorted_se  = (int2*)alloc((size_t)(N_EDGES + 8) * 8);

  const int pre_blocks = PRE_ATOM_NB + PRE_WCONV_NB + PRE_GB_NB;
  k_pre<<<pre_blocks, 384, 0, stream>>>(x, atom_emb, h0_bf, W, wt, batch, gs);
  k_cnt<<<NBLKA, 256, 0, stream>>>(ei, ghist);
  k_sscan<<<1, 256, 0, stream>>>(ghist, bucket_base, row_start);
  k_coarse<<<NBLKA, 256, 0, stream>>>(ei, ea, ghist, bucket_base, tmp_se);
  k_fine<<<NCOARSE, 256, 0, stream>>>(tmp_se, bucket_base, row_start, sorted_se);

  unsigned short* hib = h0_bf;
  unsigned short* hob = h1_bf;
  const int gemm_blocks = (N_NODES + GROWS - 1) / GROWS;  // 782
  for (int layer = 0; layer < 3; ++layer) {
    k_agg<<<N_NODES / 16, 256, 0, stream>>>(sorted_se, row_start, bond_emb + layer * 72,
                                            hib, t_bf);
    k_gemm<<<gemm_blocks, 512, 0, stream>>>(
        t_bf, wt + (size_t)layer * 128 * TDIM, b + layer * 3 * EMB,
        hib, hob, layer < 2 ? 1 : 0);
    unsigned short* tb = hib; hib = hob; hob = tb;
  }
  // final h is in hib (h1_bf after 3 swaps)

  k_head<<<N_GRAPHS, 128, 0, stream>>>(hib, gs, fc1_w, fc1_b, fc2_w, fc2_b, out);
}

// Round 10
// 320.479 us; speedup vs baseline: 1.1179x; 1.1179x over previous
//
#include <hip/hip_runtime.h>

#define N_NODES 50000
#define N_EDGES 600000
#define N_GRAPHS 2048
#define EMB 128
#define TDIM 384
#define TS_LD 392               // padded LDS row stride (shorts): 2-way bank alias only
#define HN (N_NODES * EMB)
#define GROWS 64                // k_gemm rows per block

// bucket-sort CSR build (atomic-free; replaces hist+scan+scatter)
#define EPB 2048                               // edges per count/scatter block
#define NBLKA ((N_EDGES + EPB - 1) / EPB)      // 293
#define NCOARSE ((N_NODES + 255) / 256)        // 196 coarse buckets (dst>>8)
#define SCAN_TOT (NCOARSE * NBLKA)             // 57428 flat counters
#define SC2_NB ((SCAN_TOT + 255) / 256)        // 225

// merged-prepass block ranges (384 threads/block)
#define PRE_ATOM_NB 8334        // 6 nodes/block, FULL wave per node (async LDS gathers)
#define PRE_WCONV_NB 384        // one (layer,col) per block
#define PRE_GB_NB 131           // ceil(50000/384)

typedef __attribute__((ext_vector_type(8))) short bf16x8;
typedef __attribute__((ext_vector_type(4))) float f32x4;
#define MFMA_BF16(a, b, c) __builtin_amdgcn_mfma_f32_16x16x32_bf16(a, b, c, 0, 0, 0)

#define AS1 __attribute__((address_space(1)))
#define AS3 __attribute__((address_space(3)))
__device__ inline void gl_lds16(const void* g, void* l) {
  // async global->LDS, 16B/lane: LDS dest = l + lane*16 (wave-uniform base), no dest VGPRs
  __builtin_amdgcn_global_load_lds((const AS1 void*)g, (AS3 void*)l, 16, 0, 0);
}

__device__ inline unsigned short f2bf(float f) {
  unsigned int u = __float_as_uint(f);
  u += 0x7fffu + ((u >> 16) & 1u);   // round to nearest even
  return (unsigned short)(u >> 16);
}
__device__ inline float bf2f(unsigned short b) {
  return __uint_as_float(((unsigned int)b) << 16);
}
__device__ inline bf16x8 pack8(float4 lo, float4 hi) {
  bf16x8 r;
  r[0] = (short)f2bf(lo.x); r[1] = (short)f2bf(lo.y);
  r[2] = (short)f2bf(lo.z); r[3] = (short)f2bf(lo.w);
  r[4] = (short)f2bf(hi.x); r[5] = (short)f2bf(hi.y);
  r[6] = (short)f2bf(hi.z); r[7] = (short)f2bf(hi.w);
  return r;
}

// ---------------- merged prepass: atom-encoder | W-transpose | graph-bounds ----------------
// Hist REMOVED (rounds 0-8: every global-atomic hist variant pinned at 43-52us ~= the
// ~14 G atomics/s device ceiling). CSR build is atomic-free bucket sort below.
__global__ __launch_bounds__(384) void k_pre(const int* __restrict__ x,
                                             const float* __restrict__ atom_emb,
                                             unsigned short* __restrict__ h_bf,
                                             const float* __restrict__ W,
                                             unsigned short* __restrict__ wt,
                                             const int* __restrict__ batch,
                                             int* __restrict__ gs) {
  __shared__ float sb[6 * 1280];   // 30 KB: 6 waves x (9 rows of 128f + scratch tail)
  int blk = blockIdx.x;
  if (blk < PRE_ATOM_NB) {
    const int wv = threadIdx.x >> 6;
    const int lane = threadIdx.x & 63;
    int n = blk * 6 + wv;
    if (n < N_NODES) {
      const int nu = __builtin_amdgcn_readfirstlane(n);
      const int* xr = x + nu * 9;
      int ix[9];
#pragma unroll
      for (int c = 0; c < 9; ++c) ix[c] = xr[c];   // wave-uniform -> s_loads
      float* wbase = sb + wv * 1280;
      const int half = lane >> 5;       // 0: lanes 0-31, 1: lanes 32-63
      const int sub16 = lane & 31;      // 16B slot within the row
#pragma unroll
      for (int j = 0; j < 4; ++j) {
        int c = 2 * j + half;
        const float* g = atom_emb + (size_t)(c * 100 + ix[c]) * EMB + sub16 * 4;
        gl_lds16(g, wbase + j * 256);   // row 2j -> +j*1024B, row 2j+1 -> +j*1024B+512B
      }
      {  // row 8: both halves load the same 512B (lanes 32-63 land in scratch tail)
        const float* g = atom_emb + (size_t)(8 * 100 + ix[8]) * EMB + sub16 * 4;
        gl_lds16(g, wbase + 1024);
      }
      asm volatile("s_waitcnt vmcnt(0)" ::: "memory");
      float2 acc = {0.f, 0.f};
#pragma unroll
      for (int c = 0; c < 9; ++c) {     // row c at wbase + c*128 floats
        float2 v = *(const float2*)(wbase + c * 128 + lane * 2);
        acc.x += v.x; acc.y += v.y;
      }
      *(ushort2*)(h_bf + (size_t)nu * EMB + lane * 2) = ushort2{f2bf(acc.x), f2bf(acc.y)};
    }
    return;
  }
  blk -= PRE_ATOM_NB;
  if (blk < PRE_WCONV_NB) {
    int layer = blk >> 7, c = blk & 127, k = threadIdx.x;
    float v = W[(((layer * 3 + (k >> 7)) * 128) + (k & 127)) * 128 + c];
    wt[(size_t)blk * 384 + k] = f2bf(v);
    return;
  }
  blk -= PRE_WCONV_NB;
  {
    int i = blk * 384 + threadIdx.x;
    if (i < N_NODES) {
      int b = batch[i];
      int bp = (i == 0) ? -1 : batch[i - 1];
      for (int g = bp + 1; g <= b; ++g) gs[g] = i;
      if (i == N_NODES - 1) {
        for (int g = b + 1; g <= N_GRAPHS; ++g) gs[g] = N_NODES;
      }
    }
  }
}

// ---------------- bucket-sort CSR build (no global atomics) ----------------
// Pass A: per-block LDS hist of coarse digit dst>>8.
__global__ __launch_bounds__(256) void k_cnt(const int* __restrict__ ei,
                                             int* __restrict__ ghist) {
  __shared__ int h[256];
  const int t = threadIdx.x;
  h[t] = 0;
  __syncthreads();
  const int base = blockIdx.x * EPB;
#pragma unroll
  for (int k = 0; k < 8; ++k) {
    int e = base + k * 256 + t;
    if (e < N_EDGES) atomicAdd(&h[ei[N_EDGES + e] >> 8], 1);   // LDS atomic
  }
  __syncthreads();
  if (t < NCOARSE) ghist[(size_t)t * NBLKA + blockIdx.x] = h[t];
}

// Pass B: GRID-WIDE flat exclusive scan of ghist (digit-major, 57428 ints).
// Round-9's k_sscan did this with a 1-block serial dependent-load chain: 44us at 0.1%
// of every pipe. Same scan pattern as the old CSR scan -- 3 parallel passes, ~4us.
__global__ __launch_bounds__(256) void k_gscan_a(int* __restrict__ ghist,
                                                 int* __restrict__ partials) {
  __shared__ int s[256];
  const int t = threadIdx.x;
  const int i = blockIdx.x * 256 + t;
  int v = (i < SCAN_TOT) ? ghist[i] : 0;
  s[t] = v;
  __syncthreads();
  for (int off = 1; off < 256; off <<= 1) {
    int u = (t >= off) ? s[t - off] : 0;
    __syncthreads();
    s[t] += u;
    __syncthreads();
  }
  if (i < SCAN_TOT) ghist[i] = s[t] - v;          // exclusive within block
  if (t == 255) partials[blockIdx.x] = s[255];
}

__global__ __launch_bounds__(256) void k_gscan_b(int* __restrict__ partials,
                                                 int* __restrict__ bucket_base,
                                                 int* __restrict__ row_start) {
  __shared__ int s[256];
  const int t = threadIdx.x;
  int v = (t < SC2_NB) ? partials[t] : 0;
  s[t] = v;
  __syncthreads();
  for (int off = 1; off < 256; off <<= 1) {
    int u = (t >= off) ? s[t - off] : 0;
    __syncthreads();
    s[t] += u;
    __syncthreads();
  }
  if (t < SC2_NB) partials[t] = s[t] - v;         // exclusive block offsets
  if (t == 0) { bucket_base[NCOARSE] = N_EDGES; row_start[N_NODES] = N_EDGES; }
}

__global__ __launch_bounds__(256) void k_gscan_c(int* __restrict__ ghist,
                                                 const int* __restrict__ partials,
                                                 int* __restrict__ bucket_base) {
  const int i = blockIdx.x * 256 + threadIdx.x;
  if (i < SCAN_TOT) {
    int g = ghist[i] + partials[blockIdx.x];      // global exclusive scan value
    ghist[i] = g;
    int d = i / NBLKA;
    if (i - d * NBLKA == 0) bucket_base[d] = g;   // digit boundary
  }
}

// Pass C: scatter edges into coarse-bucket order; payload packed {dst|eap<<16, src}.
// ghist now holds the GLOBAL exclusive scan -> position is ghist value + local rank.
__global__ __launch_bounds__(256) void k_coarse(const int* __restrict__ ei,
                                                const int* __restrict__ ea,
                                                const int* __restrict__ ghist,
                                                int2* __restrict__ tmp) {
  __shared__ int cnt[256];
  const int t = threadIdx.x;
  cnt[t] = 0;
  __syncthreads();
  const int base = blockIdx.x * EPB;
#pragma unroll
  for (int k = 0; k < 8; ++k) {
    int e = base + k * 256 + t;
    if (e < N_EDGES) {
      int dst = ei[N_EDGES + e];
      int d = dst >> 8;
      int r = atomicAdd(&cnt[d], 1);   // LDS atomic: block-local rank in bucket
      int pos = ghist[(size_t)d * NBLKA + blockIdx.x] + r;
      int eap = ea[e * 3 + 0] | (ea[e * 3 + 1] << 3) | (ea[e * 3 + 2] << 6);
      tmp[pos] = int2{dst | (eap << 16), ei[e]};
    }
  }
}

// Pass D: one block per coarse bucket -- fine hist (dst&255), LDS scan writes
// row_start DIRECTLY, then scatter into final sorted_se {src, eap}.
__global__ __launch_bounds__(256) void k_fine(const int2* __restrict__ tmp,
                                              const int* __restrict__ bucket_base,
                                              int* __restrict__ row_start,
                                              int2* __restrict__ sorted_se) {
  __shared__ int h[256];
  __shared__ int s[256];
  __shared__ int ex[256];
  const int t = threadIdx.x;
  const int d = blockIdx.x;
  const int b0 = bucket_base[d], b1 = bucket_base[d + 1];
  h[t] = 0;
  __syncthreads();
  for (int i = b0 + t; i < b1; i += 256) atomicAdd(&h[tmp[i].x & 255], 1);
  __syncthreads();
  s[t] = h[t];
  __syncthreads();
  for (int off = 1; off < 256; off <<= 1) {
    int v = (t >= off) ? s[t - off] : 0;
    __syncthreads();
    s[t] += v;
    __syncthreads();
  }
  ex[t] = s[t] - h[t];                 // exclusive offsets within bucket
  int node = d * 256 + t;
  if (node < N_NODES) row_start[node] = b0 + ex[t];
  h[t] = 0;
  __syncthreads();
  for (int i = b0 + t; i < b1; i += 256) {
    int2 r = tmp[i];
    int f = r.x & 255;
    int pos = b0 + ex[f] + atomicAdd(&h[f], 1);   // LDS atomic
    sorted_se[pos] = int2{r.y, (r.x >> 16) & 511};
  }
}

// ---------------- Edge aggregation: QUARTER-WAVE per node, unroll-8 (round-5 local optimum) --------
// Ledger: bucketing (r6) -8us, unroll-16 (r7) -27us, half-wave (r0) -7us -- all reverted.
// 16 lanes x bf16x8 = full 256B row per gather; 4 nodes x 8 edges = 8 KB in flight/wave.
__global__ __launch_bounds__(256) void k_agg(const int2* __restrict__ sorted_se,
                                             const int* __restrict__ row_start,
                                             const float* __restrict__ bl,  // bond_emb[layer]: [3][8][3]
                                             const unsigned short* __restrict__ h_bf,
                                             unsigned short* __restrict__ t_bf) {
  __shared__ float4 combo[512];  // 8 KB
  for (int c = threadIdx.x; c < 512; c += 256) {
    int a0 = c & 7, a1 = (c >> 3) & 7, a2 = (c >> 6) & 7;
    combo[c] = float4{bl[a0 * 3 + 0] + bl[24 + a1 * 3 + 0] + bl[48 + a2 * 3 + 0],
                      bl[a0 * 3 + 1] + bl[24 + a1 * 3 + 1] + bl[48 + a2 * 3 + 1],
                      bl[a0 * 3 + 2] + bl[24 + a1 * 3 + 2] + bl[48 + a2 * 3 + 2], 0.f};
  }
  __syncthreads();
  const int node = blockIdx.x * 16 + (threadIdx.x >> 4);  // quarter-wave per node
  const int sub = threadIdx.x & 15;                       // cols sub*8..+7
  const int beg = row_start[node], end = row_start[node + 1];
  float4 l0 = {0.f, 0.f, 0.f, 0.f}, h0 = l0;   // channel 0: cols lo/hi
  float4 l1 = l0, h1 = l0;                     // channel 1
  float4 l2 = l0, h2 = l0;                     // channel 2
  int e = beg;
  const int full_end = beg + ((end - beg) & ~7);
  for (; e < full_end; e += 8) {           // fast path: no bounds logic
    int2 se[8];
#pragma unroll
    for (int j = 0; j < 8; ++j) se[j] = sorted_se[e + j];
    bf16x8 u[8];
#pragma unroll
    for (int j = 0; j < 8; ++j)
      u[j] = *(const bf16x8*)(h_bf + (size_t)se[j].x * EMB + sub * 8);
#pragma unroll
    for (int j = 0; j < 8; ++j) {
      float4 w = combo[se[j].y];
      float4 vlo = {bf2f((unsigned short)u[j][0]), bf2f((unsigned short)u[j][1]),
                    bf2f((unsigned short)u[j][2]), bf2f((unsigned short)u[j][3])};
      float4 vhi = {bf2f((unsigned short)u[j][4]), bf2f((unsigned short)u[j][5]),
                    bf2f((unsigned short)u[j][6]), bf2f((unsigned short)u[j][7])};
      l0 += vlo * w.x; h0 += vhi * w.x;
      l1 += vlo * w.y; h1 += vhi * w.y;
      l2 += vlo * w.z; h2 += vhi * w.z;
    }
  }
  if (e < end) {                           // tail chunk: clamped + weight-selected
    int2 se[8];
#pragma unroll
    for (int j = 0; j < 8; ++j) {
      int idx = e + j;
      se[j] = sorted_se[idx < end ? idx : end - 1];
    }
    bf16x8 u[8];
#pragma unroll
    for (int j = 0; j < 8; ++j)
      u[j] = *(const bf16x8*)(h_bf + (size_t)se[j].x * EMB + sub * 8);
#pragma unroll
    for (int j = 0; j < 8; ++j) {
      float4 w = (e + j < end) ? combo[se[j].y] : float4{0.f, 0.f, 0.f, 0.f};
      float4 vlo = {bf2f((unsigned short)u[j][0]), bf2f((unsigned short)u[j][1]),
                    bf2f((unsigned short)u[j][2]), bf2f((unsigned short)u[j][3])};
      float4 vhi = {bf2f((unsigned short)u[j][4]), bf2f((unsigned short)u[j][5]),
                    bf2f((unsigned short)u[j][6]), bf2f((unsigned short)u[j][7])};
      l0 += vlo * w.x; h0 += vhi * w.x;
      l1 += vlo * w.y; h1 += vhi * w.y;
      l2 += vlo * w.z; h2 += vhi * w.z;
    }
  }
  size_t base = (size_t)node * TDIM + sub * 8;
  *(bf16x8*)(t_bf + base)       = pack8(l0, h0);
  *(bf16x8*)(t_bf + base + 128) = pack8(l1, h1);
  *(bf16x8*)(t_bf + base + 256) = pack8(l2, h2);
}

// ---------------- MFMA GEMM: 64-row blocks (halved L2 weight re-fetch) ----------------
// Block 512 thr = 8 waves; 64 nodes/block; grid 782; LDS 50 KB -> 3 blocks/CU (24 waves).
// Wave wv owns cols wv*16..+15: 12 resident B-frags amortized over 4 row-tiles x 12
// MFMAs = 48 MFMAs. A-frag: A[m=lane&15][k=(lane>>4)*8+j]; B-frag: B[k][n=lane&15];
// C/D: col=lane&15, row=(lane>>4)*4+reg.
__global__ __launch_bounds__(512) void k_gemm(const unsigned short* __restrict__ t_bf,
                                              const unsigned short* __restrict__ wt,  // [128][384]
                                              const float* __restrict__ bl,  // [3][128]
                                              const unsigned short* __restrict__ h_in_bf,
                                              unsigned short* __restrict__ h_out_bf,
                                              int do_relu) {
  __shared__ unsigned short ts[GROWS * TS_LD];   // 50.2 KB
  const int nb = blockIdx.x * GROWS;
  for (int i = threadIdx.x; i < GROWS * 48; i += 512) {
    int r = i / 48, cc = i % 48;
    bf16x8 v = {};
    int row = nb + r;
    if (row < N_NODES) v = *(const bf16x8*)(t_bf + (size_t)row * TDIM + cc * 8);
    *(bf16x8*)(ts + r * TS_LD + cc * 8) = v;
  }
  __syncthreads();

  const int wv = threadIdx.x >> 6;
  const int lane = threadIdx.x & 63;
  const int m = lane & 15;
  const int kq = lane >> 4;
  const int c = wv * 16 + m;

  const unsigned short* pB = wt + (size_t)c * TDIM + kq * 8;
  bf16x8 B[12];
#pragma unroll
  for (int kc = 0; kc < 12; ++kc) B[kc] = *(const bf16x8*)(pB + kc * 32);

  const float bias = bl[c] + bl[128 + c] + bl[256 + c];

#pragma unroll
  for (int rt = 0; rt < 4; ++rt) {
    const unsigned short* pA = ts + (rt * 16 + m) * TS_LD + kq * 8;
    bf16x8 A[12];
#pragma unroll
    for (int kc = 0; kc < 12; ++kc) A[kc] = *(const bf16x8*)(pA + kc * 32);
    f32x4 acc = {0.f, 0.f, 0.f, 0.f};
#pragma unroll
    for (int kc = 0; kc < 12; ++kc) acc = MFMA_BF16(A[kc], B[kc], acc);
#pragma unroll
    for (int r = 0; r < 4; ++r) {
      int row = nb + rt * 16 + kq * 4 + r;
      if (row < N_NODES) {
        size_t idx = (size_t)row * EMB + c;
        float v = acc[r] + bias;
        if (do_relu) v = fmaxf(v, 0.f);
        float hn = bf2f(h_in_bf[idx]) + v;
        h_out_bf[idx] = f2bf(hn);
      }
    }
  }
}

// ---------------- fused mean-pool + head: block g reduces its contiguous node range ----------------
__global__ __launch_bounds__(128) void k_head(const unsigned short* __restrict__ h_bf,
                                              const int* __restrict__ gs,
                                              const float* __restrict__ fc1_w,
                                              const float* __restrict__ fc1_b,
                                              const float* __restrict__ fc2_w,
                                              const float* __restrict__ fc2_b,
                                              float* __restrict__ out) {
  __shared__ float hg[EMB];
  __shared__ float red[EMB];
  int g = blockIdx.x, e = threadIdx.x;
  int ns = gs[g], ne = gs[g + 1];
  float acc = 0.f;
  for (int n = ns; n < ne; ++n) acc += bf2f(h_bf[(size_t)n * EMB + e]);
  float cnt = fmaxf((float)(ne - ns), 1.f);
  hg[e] = acc / cnt;
  __syncthreads();
  float a2 = fc1_b[e];
  for (int j = 0; j < EMB; ++j) a2 += hg[j] * fc1_w[j * EMB + e];
  red[e] = a2 * fc2_w[e];
  __syncthreads();
  for (int s = 64; s > 0; s >>= 1) {
    if (e < s) red[e] += red[e + s];
    __syncthreads();
  }
  if (e == 0) out[g] = red[0] + fc2_b[0];
}

extern "C" void kernel_launch(void* const* d_in, const int* in_sizes, int n_in,
                              void* d_out, int out_size, void* d_ws, size_t ws_size,
                              hipStream_t stream) {
  const int*   x        = (const int*)d_in[0];
  const int*   ei       = (const int*)d_in[1];
  const int*   ea       = (const int*)d_in[2];
  const int*   batch    = (const int*)d_in[3];
  const float* atom_emb = (const float*)d_in[4];
  const float* bond_emb = (const float*)d_in[5];
  const float* W        = (const float*)d_in[6];
  const float* b        = (const float*)d_in[7];
  const float* fc1_w    = (const float*)d_in[8];
  const float* fc1_b    = (const float*)d_in[9];
  const float* fc2_w    = (const float*)d_in[10];
  const float* fc2_b    = (const float*)d_in[11];
  float* out = (float*)d_out;

  char* p = (char*)d_ws;
  auto alloc = [&](size_t bytes) { char* r = p; p += (bytes + 255) & ~(size_t)255; return r; };
  unsigned short* h0_bf      = (unsigned short*)alloc((size_t)HN * 2);
  unsigned short* h1_bf      = (unsigned short*)alloc((size_t)HN * 2);
  unsigned short* t_bf       = (unsigned short*)alloc((size_t)N_NODES * TDIM * 2);
  unsigned short* wt         = (unsigned short*)alloc((size_t)3 * 128 * TDIM * 2);
  int*            gs         = (int*)alloc((size_t)(N_GRAPHS + 1) * 4);
  int*            row_start  = (int*)alloc((size_t)(N_NODES + 1) * 4);
  int*            ghist      = (int*)alloc((size_t)SCAN_TOT * 4);          // ~230 KB
  int*            spart      = (int*)alloc((size_t)SC2_NB * 4);
  int*            bucket_base= (int*)alloc((size_t)(NCOARSE + 1) * 4);
  int2*           tmp_se     = (int2*)alloc((size_t)N_EDGES * 8);          // 4.8 MB
  int2*           sorted_se  = (int2*)alloc((size_t)(N_EDGES + 8) * 8);

  const int pre_blocks = PRE_ATOM_NB + PRE_WCONV_NB + PRE_GB_NB;
  k_pre<<<pre_blocks, 384, 0, stream>>>(x, atom_emb, h0_bf, W, wt, batch, gs);
  k_cnt<<<NBLKA, 256, 0, stream>>>(ei, ghist);
  k_gscan_a<<<SC2_NB, 256, 0, stream>>>(ghist, spart);
  k_gscan_b<<<1, 256, 0, stream>>>(spart, bucket_base, row_start);
  k_gscan_c<<<SC2_NB, 256, 0, stream>>>(ghist, spart, bucket_base);
  k_coarse<<<NBLKA, 256, 0, stream>>>(ei, ea, ghist, tmp_se);
  k_fine<<<NCOARSE, 256, 0, stream>>>(tmp_se, bucket_base, row_start, sorted_se);

  unsigned short* hib = h0_bf;
  unsigned short* hob = h1_bf;
  const int gemm_blocks = (N_NODES + GROWS - 1) / GROWS;  // 782
  for (int layer = 0; layer < 3; ++layer) {
    k_agg<<<N_NODES / 16, 256, 0, stream>>>(sorted_se, row_start, bond_emb + layer * 72,
                                            hib, t_bf);
    k_gemm<<<gemm_blocks, 512, 0, stream>>>(
        t_bf, wt + (size_t)layer * 128 * TDIM, b + layer * 3 * EMB,
        hib, hob, layer < 2 ? 1 : 0);
    unsigned short* tb = hib; hib = hob; hob = tb;
  }
  // final h is in hib (h1_bf after 3 swaps)

  k_head<<<N_GRAPHS, 128, 0, stream>>>(hib, gs, fc1_w, fc1_b, fc2_w, fc2_b, out);
}

// Round 11
// 315.119 us; speedup vs baseline: 1.1369x; 1.0170x over previous
//
#include <hip/hip_runtime.h>

#define N_NODES 50000
#define N_EDGES 600000
#define N_GRAPHS 2048
#define EMB 128
#define TDIM 384
#define TS_LD 392               // padded LDS row stride (shorts): 2-way bank alias only
#define HN (N_NODES * EMB)
#define GROWS 64                // k_gemm rows per block

// bucket-sort CSR build (atomic-free; replaces hist+scan+scatter)
#define EPB 2048                               // edges per count/scatter block
#define NBLKA ((N_EDGES + EPB - 1) / EPB)      // 293
#define NCOARSE ((N_NODES + 255) / 256)        // 196 coarse buckets (dst>>8)
#define SCAN_TOT (NCOARSE * NBLKA)             // 57428 flat counters
#define SC2_NB ((SCAN_TOT + 255) / 256)        // 225

// merged-prepass block ranges (384 threads/block)
#define PRE_ATOM_NB 8334        // 6 nodes/block, FULL wave per node (async LDS gathers)
#define PRE_CNT_NB NBLKA        // coarse-digit hist blocks (merged k_cnt)
#define PRE_WCONV_NB 384        // one (layer,col) per block
#define PRE_GB_NB 131           // ceil(50000/384)

typedef __attribute__((ext_vector_type(8))) short bf16x8;
typedef __attribute__((ext_vector_type(4))) float f32x4;
#define MFMA_BF16(a, b, c) __builtin_amdgcn_mfma_f32_16x16x32_bf16(a, b, c, 0, 0, 0)

#define AS1 __attribute__((address_space(1)))
#define AS3 __attribute__((address_space(3)))
__device__ inline void gl_lds16(const void* g, void* l) {
  // async global->LDS, 16B/lane: LDS dest = l + lane*16 (wave-uniform base), no dest VGPRs
  __builtin_amdgcn_global_load_lds((const AS1 void*)g, (AS3 void*)l, 16, 0, 0);
}

__device__ inline unsigned short f2bf(float f) {
  unsigned int u = __float_as_uint(f);
  u += 0x7fffu + ((u >> 16) & 1u);   // round to nearest even
  return (unsigned short)(u >> 16);
}
__device__ inline float bf2f(unsigned short b) {
  return __uint_as_float(((unsigned int)b) << 16);
}
__device__ inline bf16x8 pack8(float4 lo, float4 hi) {
  bf16x8 r;
  r[0] = (short)f2bf(lo.x); r[1] = (short)f2bf(lo.y);
  r[2] = (short)f2bf(lo.z); r[3] = (short)f2bf(lo.w);
  r[4] = (short)f2bf(hi.x); r[5] = (short)f2bf(hi.y);
  r[6] = (short)f2bf(hi.z); r[7] = (short)f2bf(hi.w);
  return r;
}

// ---------------- merged prepass: atom-encoder | coarse-hist | W-transpose | graph-bounds -----
// Global-atomic hist removed entirely (rounds 0-8: pinned at ~14 G atomics/s). The
// coarse COUNT pass of the bucket sort is folded in here as its own block range
// (independent outputs; saves one launch and overlaps with the atom phase).
__global__ __launch_bounds__(384) void k_pre(const int* __restrict__ x,
                                             const float* __restrict__ atom_emb,
                                             unsigned short* __restrict__ h_bf,
                                             const int* __restrict__ ei,
                                             int* __restrict__ ghist,
                                             const float* __restrict__ W,
                                             unsigned short* __restrict__ wt,
                                             const int* __restrict__ batch,
                                             int* __restrict__ gs) {
  __shared__ float sb[6 * 1280];   // 30 KB: 6 waves x (9 rows of 128f + scratch tail)
  int blk = blockIdx.x;
  if (blk < PRE_ATOM_NB) {
    const int wv = threadIdx.x >> 6;
    const int lane = threadIdx.x & 63;
    int n = blk * 6 + wv;
    if (n < N_NODES) {
      const int nu = __builtin_amdgcn_readfirstlane(n);
      const int* xr = x + nu * 9;
      int ix[9];
#pragma unroll
      for (int c = 0; c < 9; ++c) ix[c] = xr[c];   // wave-uniform -> s_loads
      float* wbase = sb + wv * 1280;
      const int half = lane >> 5;       // 0: lanes 0-31, 1: lanes 32-63
      const int sub16 = lane & 31;      // 16B slot within the row
#pragma unroll
      for (int j = 0; j < 4; ++j) {
        int c = 2 * j + half;
        const float* g = atom_emb + (size_t)(c * 100 + ix[c]) * EMB + sub16 * 4;
        gl_lds16(g, wbase + j * 256);   // row 2j -> +j*1024B, row 2j+1 -> +j*1024B+512B
      }
      {  // row 8: both halves load the same 512B (lanes 32-63 land in scratch tail)
        const float* g = atom_emb + (size_t)(8 * 100 + ix[8]) * EMB + sub16 * 4;
        gl_lds16(g, wbase + 1024);
      }
      asm volatile("s_waitcnt vmcnt(0)" ::: "memory");
      float2 acc = {0.f, 0.f};
#pragma unroll
      for (int c = 0; c < 9; ++c) {     // row c at wbase + c*128 floats
        float2 v = *(const float2*)(wbase + c * 128 + lane * 2);
        acc.x += v.x; acc.y += v.y;
      }
      *(ushort2*)(h_bf + (size_t)nu * EMB + lane * 2) = ushort2{f2bf(acc.x), f2bf(acc.y)};
    }
    return;
  }
  blk -= PRE_ATOM_NB;
  if (blk < PRE_CNT_NB) {               // merged k_cnt: LDS hist of dst>>8
    int* h = (int*)sb;
    const int t = threadIdx.x;
    if (t < 256) h[t] = 0;
    __syncthreads();
    const int base = blk * EPB;
#pragma unroll
    for (int k = 0; k < 6; ++k) {       // 6*384 = 2304 covers EPB=2048
      int o = k * 384 + t;
      int e = base + o;
      if (o < EPB && e < N_EDGES) atomicAdd(&h[ei[N_EDGES + e] >> 8], 1);  // LDS atomic
    }
    __syncthreads();
    if (t < NCOARSE) ghist[(size_t)t * NBLKA + blk] = h[t];
    return;
  }
  blk -= PRE_CNT_NB;
  if (blk < PRE_WCONV_NB) {
    int layer = blk >> 7, c = blk & 127, k = threadIdx.x;
    float v = W[(((layer * 3 + (k >> 7)) * 128) + (k & 127)) * 128 + c];
    wt[(size_t)blk * 384 + k] = f2bf(v);
    return;
  }
  blk -= PRE_WCONV_NB;
  {
    int i = blk * 384 + threadIdx.x;
    if (i < N_NODES) {
      int b = batch[i];
      int bp = (i == 0) ? -1 : batch[i - 1];
      for (int g = bp + 1; g <= b; ++g) gs[g] = i;
      if (i == N_NODES - 1) {
        for (int g = b + 1; g <= N_GRAPHS; ++g) gs[g] = N_NODES;
      }
    }
  }
}

// ---------------- bucket-sort CSR build (no global atomics) ----------------
// Pass B: GRID-WIDE flat exclusive scan of ghist (digit-major, 57428 ints).
__global__ __launch_bounds__(256) void k_gscan_a(int* __restrict__ ghist,
                                                 int* __restrict__ partials) {
  __shared__ int s[256];
  const int t = threadIdx.x;
  const int i = blockIdx.x * 256 + t;
  int v = (i < SCAN_TOT) ? ghist[i] : 0;
  s[t] = v;
  __syncthreads();
  for (int off = 1; off < 256; off <<= 1) {
    int u = (t >= off) ? s[t - off] : 0;
    __syncthreads();
    s[t] += u;
    __syncthreads();
  }
  if (i < SCAN_TOT) ghist[i] = s[t] - v;          // exclusive within block
  if (t == 255) partials[blockIdx.x] = s[255];
}

__global__ __launch_bounds__(256) void k_gscan_b(int* __restrict__ partials,
                                                 int* __restrict__ bucket_base,
                                                 int* __restrict__ row_start) {
  __shared__ int s[256];
  const int t = threadIdx.x;
  int v = (t < SC2_NB) ? partials[t] : 0;
  s[t] = v;
  __syncthreads();
  for (int off = 1; off < 256; off <<= 1) {
    int u = (t >= off) ? s[t - off] : 0;
    __syncthreads();
    s[t] += u;
    __syncthreads();
  }
  if (t < SC2_NB) partials[t] = s[t] - v;         // exclusive block offsets
  if (t == 0) { bucket_base[NCOARSE] = N_EDGES; row_start[N_NODES] = N_EDGES; }
}

__global__ __launch_bounds__(256) void k_gscan_c(int* __restrict__ ghist,
                                                 const int* __restrict__ partials,
                                                 int* __restrict__ bucket_base) {
  const int i = blockIdx.x * 256 + threadIdx.x;
  if (i < SCAN_TOT) {
    int g = ghist[i] + partials[blockIdx.x];      // global exclusive scan value
    ghist[i] = g;
    int d = i / NBLKA;
    if (i - d * NBLKA == 0) bucket_base[d] = g;   // digit boundary
  }
}

// Pass C: scatter edges into coarse-bucket order; payload packed {dst|eap<<16, src}.
__global__ __launch_bounds__(256) void k_coarse(const int* __restrict__ ei,
                                                const int* __restrict__ ea,
                                                const int* __restrict__ ghist,
                                                int2* __restrict__ tmp) {
  __shared__ int cnt[256];
  const int t = threadIdx.x;
  cnt[t] = 0;
  __syncthreads();
  const int base = blockIdx.x * EPB;
#pragma unroll
  for (int k = 0; k < 8; ++k) {
    int e = base + k * 256 + t;
    if (e < N_EDGES) {
      int dst = ei[N_EDGES + e];
      int d = dst >> 8;
      int r = atomicAdd(&cnt[d], 1);   // LDS atomic: block-local rank in bucket
      int pos = ghist[(size_t)d * NBLKA + blockIdx.x] + r;
      int eap = ea[e * 3 + 0] | (ea[e * 3 + 1] << 3) | (ea[e * 3 + 2] << 6);
      tmp[pos] = int2{dst | (eap << 16), ei[e]};
    }
  }
}

// Pass D: one block per coarse bucket -- fine hist (dst&255), LDS scan writes
// row_start DIRECTLY, then scatter into final sorted_se {src, eap}.
__global__ __launch_bounds__(256) void k_fine(const int2* __restrict__ tmp,
                                              const int* __restrict__ bucket_base,
                                              int* __restrict__ row_start,
                                              int2* __restrict__ sorted_se) {
  __shared__ int h[256];
  __shared__ int s[256];
  __shared__ int ex[256];
  const int t = threadIdx.x;
  const int d = blockIdx.x;
  const int b0 = bucket_base[d], b1 = bucket_base[d + 1];
  h[t] = 0;
  __syncthreads();
  for (int i = b0 + t; i < b1; i += 256) atomicAdd(&h[tmp[i].x & 255], 1);
  __syncthreads();
  s[t] = h[t];
  __syncthreads();
  for (int off = 1; off < 256; off <<= 1) {
    int v = (t >= off) ? s[t - off] : 0;
    __syncthreads();
    s[t] += v;
    __syncthreads();
  }
  ex[t] = s[t] - h[t];                 // exclusive offsets within bucket
  int node = d * 256 + t;
  if (node < N_NODES) row_start[node] = b0 + ex[t];
  h[t] = 0;
  __syncthreads();
  for (int i = b0 + t; i < b1; i += 256) {
    int2 r = tmp[i];
    int f = r.x & 255;
    int pos = b0 + ex[f] + atomicAdd(&h[f], 1);   // LDS atomic
    sorted_se[pos] = int2{r.y, (r.x >> 16) & 511};
  }
}

// ---------------- Edge aggregation: QUARTER-WAVE per node, unroll-8, se-PIPELINED ----------------
// Config ledger: bucketing (r6) -8us, unroll-16 (r7) -27us, half-wave (r0) -7us.
// New (r11): 2-stage software pipeline -- next chunk's se[8] loads issue during the
// current chunk's gathers/FMAs, removing the se L2 latency (~200-300cy) from the
// per-chunk serial chain (was: se wait -> gather wait -> FMA). +16 VGPR only.
// Prologue (row_start + first se) hoisted above the combo fill to hide under it.
__global__ __launch_bounds__(256) void k_agg(const int2* __restrict__ sorted_se,
                                             const int* __restrict__ row_start,
                                             const float* __restrict__ bl,  // bond_emb[layer]: [3][8][3]
                                             const unsigned short* __restrict__ h_bf,
                                             unsigned short* __restrict__ t_bf) {
  __shared__ float4 combo[512];  // 8 KB
  const int node = blockIdx.x * 16 + (threadIdx.x >> 4);  // quarter-wave per node
  const int sub = threadIdx.x & 15;                       // cols sub*8..+7
  const int beg = row_start[node], end = row_start[node + 1];
  int e = beg;
  const int full_end = beg + ((end - beg) & ~7);
  int2 se[8];
  if (e < full_end) {
#pragma unroll
    for (int j = 0; j < 8; ++j) se[j] = sorted_se[e + j];   // prologue, overlaps combo fill
  }
  for (int c = threadIdx.x; c < 512; c += 256) {
    int a0 = c & 7, a1 = (c >> 3) & 7, a2 = (c >> 6) & 7;
    combo[c] = float4{bl[a0 * 3 + 0] + bl[24 + a1 * 3 + 0] + bl[48 + a2 * 3 + 0],
                      bl[a0 * 3 + 1] + bl[24 + a1 * 3 + 1] + bl[48 + a2 * 3 + 1],
                      bl[a0 * 3 + 2] + bl[24 + a1 * 3 + 2] + bl[48 + a2 * 3 + 2], 0.f};
  }
  __syncthreads();
  float4 l0 = {0.f, 0.f, 0.f, 0.f}, h0 = l0;   // channel 0: cols lo/hi
  float4 l1 = l0, h1 = l0;                     // channel 1
  float4 l2 = l0, h2 = l0;                     // channel 2
  while (e < full_end) {                   // fast path: no bounds logic
    bf16x8 u[8];
#pragma unroll
    for (int j = 0; j < 8; ++j)
      u[j] = *(const bf16x8*)(h_bf + (size_t)se[j].x * EMB + sub * 8);
    e += 8;
    int2 se_n[8];
    const bool more = (e < full_end);
    if (more) {
#pragma unroll
      for (int j = 0; j < 8; ++j) se_n[j] = sorted_se[e + j];  // prefetch next chunk
    }
#pragma unroll
    for (int j = 0; j < 8; ++j) {
      float4 w = combo[se[j].y];
      float4 vlo = {bf2f((unsigned short)u[j][0]), bf2f((unsigned short)u[j][1]),
                    bf2f((unsigned short)u[j][2]), bf2f((unsigned short)u[j][3])};
      float4 vhi = {bf2f((unsigned short)u[j][4]), bf2f((unsigned short)u[j][5]),
                    bf2f((unsigned short)u[j][6]), bf2f((unsigned short)u[j][7])};
      l0 += vlo * w.x; h0 += vhi * w.x;
      l1 += vlo * w.y; h1 += vhi * w.y;
      l2 += vlo * w.z; h2 += vhi * w.z;
    }
    if (more) {
#pragma unroll
      for (int j = 0; j < 8; ++j) se[j] = se_n[j];
    }
  }
  if (e < end) {                           // tail chunk: clamped + weight-selected
    int2 st[8];
#pragma unroll
    for (int j = 0; j < 8; ++j) {
      int idx = e + j;
      st[j] = sorted_se[idx < end ? idx : end - 1];
    }
    bf16x8 u[8];
#pragma unroll
    for (int j = 0; j < 8; ++j)
      u[j] = *(const bf16x8*)(h_bf + (size_t)st[j].x * EMB + sub * 8);
#pragma unroll
    for (int j = 0; j < 8; ++j) {
      float4 w = (e + j < end) ? combo[st[j].y] : float4{0.f, 0.f, 0.f, 0.f};
      float4 vlo = {bf2f((unsigned short)u[j][0]), bf2f((unsigned short)u[j][1]),
                    bf2f((unsigned short)u[j][2]), bf2f((unsigned short)u[j][3])};
      float4 vhi = {bf2f((unsigned short)u[j][4]), bf2f((unsigned short)u[j][5]),
                    bf2f((unsigned short)u[j][6]), bf2f((unsigned short)u[j][7])};
      l0 += vlo * w.x; h0 += vhi * w.x;
      l1 += vlo * w.y; h1 += vhi * w.y;
      l2 += vlo * w.z; h2 += vhi * w.z;
    }
  }
  size_t base = (size_t)node * TDIM + sub * 8;
  *(bf16x8*)(t_bf + base)       = pack8(l0, h0);
  *(bf16x8*)(t_bf + base + 128) = pack8(l1, h1);
  *(bf16x8*)(t_bf + base + 256) = pack8(l2, h2);
}

// ---------------- MFMA GEMM: 64-row blocks (halved L2 weight re-fetch) ----------------
// Block 512 thr = 8 waves; 64 nodes/block; grid 782; LDS 50 KB -> 3 blocks/CU (24 waves).
// Wave wv owns cols wv*16..+15: 12 resident B-frags amortized over 4 row-tiles x 12
// MFMAs = 48 MFMAs. A-frag: A[m=lane&15][k=(lane>>4)*8+j]; B-frag: B[k][n=lane&15];
// C/D: col=lane&15, row=(lane>>4)*4+reg.
__global__ __launch_bounds__(512) void k_gemm(const unsigned short* __restrict__ t_bf,
                                              const unsigned short* __restrict__ wt,  // [128][384]
                                              const float* __restrict__ bl,  // [3][128]
                                              const unsigned short* __restrict__ h_in_bf,
                                              unsigned short* __restrict__ h_out_bf,
                                              int do_relu) {
  __shared__ unsigned short ts[GROWS * TS_LD];   // 50.2 KB
  const int nb = blockIdx.x * GROWS;
  for (int i = threadIdx.x; i < GROWS * 48; i += 512) {
    int r = i / 48, cc = i % 48;
    bf16x8 v = {};
    int row = nb + r;
    if (row < N_NODES) v = *(const bf16x8*)(t_bf + (size_t)row * TDIM + cc * 8);
    *(bf16x8*)(ts + r * TS_LD + cc * 8) = v;
  }
  __syncthreads();

  const int wv = threadIdx.x >> 6;
  const int lane = threadIdx.x & 63;
  const int m = lane & 15;
  const int kq = lane >> 4;
  const int c = wv * 16 + m;

  const unsigned short* pB = wt + (size_t)c * TDIM + kq * 8;
  bf16x8 B[12];
#pragma unroll
  for (int kc = 0; kc < 12; ++kc) B[kc] = *(const bf16x8*)(pB + kc * 32);

  const float bias = bl[c] + bl[128 + c] + bl[256 + c];

#pragma unroll
  for (int rt = 0; rt < 4; ++rt) {
    const unsigned short* pA = ts + (rt * 16 + m) * TS_LD + kq * 8;
    bf16x8 A[12];
#pragma unroll
    for (int kc = 0; kc < 12; ++kc) A[kc] = *(const bf16x8*)(pA + kc * 32);
    f32x4 acc = {0.f, 0.f, 0.f, 0.f};
#pragma unroll
    for (int kc = 0; kc < 12; ++kc) acc = MFMA_BF16(A[kc], B[kc], acc);
#pragma unroll
    for (int r = 0; r < 4; ++r) {
      int row = nb + rt * 16 + kq * 4 + r;
      if (row < N_NODES) {
        size_t idx = (size_t)row * EMB + c;
        float v = acc[r] + bias;
        if (do_relu) v = fmaxf(v, 0.f);
        float hn = bf2f(h_in_bf[idx]) + v;
        h_out_bf[idx] = f2bf(hn);
      }
    }
  }
}

// ---------------- fused mean-pool + head: block g reduces its contiguous node range ----------------
__global__ __launch_bounds__(128) void k_head(const unsigned short* __restrict__ h_bf,
                                              const int* __restrict__ gs,
                                              const float* __restrict__ fc1_w,
                                              const float* __restrict__ fc1_b,
                                              const float* __restrict__ fc2_w,
                                              const float* __restrict__ fc2_b,
                                              float* __restrict__ out) {
  __shared__ float hg[EMB];
  __shared__ float red[EMB];
  int g = blockIdx.x, e = threadIdx.x;
  int ns = gs[g], ne = gs[g + 1];
  float acc = 0.f;
  for (int n = ns; n < ne; ++n) acc += bf2f(h_bf[(size_t)n * EMB + e]);
  float cnt = fmaxf((float)(ne - ns), 1.f);
  hg[e] = acc / cnt;
  __syncthreads();
  float a2 = fc1_b[e];
  for (int j = 0; j < EMB; ++j) a2 += hg[j] * fc1_w[j * EMB + e];
  red[e] = a2 * fc2_w[e];
  __syncthreads();
  for (int s = 64; s > 0; s >>= 1) {
    if (e < s) red[e] += red[e + s];
    __syncthreads();
  }
  if (e == 0) out[g] = red[0] + fc2_b[0];
}

extern "C" void kernel_launch(void* const* d_in, const int* in_sizes, int n_in,
                              void* d_out, int out_size, void* d_ws, size_t ws_size,
                              hipStream_t stream) {
  const int*   x        = (const int*)d_in[0];
  const int*   ei       = (const int*)d_in[1];
  const int*   ea       = (const int*)d_in[2];
  const int*   batch    = (const int*)d_in[3];
  const float* atom_emb = (const float*)d_in[4];
  const float* bond_emb = (const float*)d_in[5];
  const float* W        = (const float*)d_in[6];
  const float* b        = (const float*)d_in[7];
  const float* fc1_w    = (const float*)d_in[8];
  const float* fc1_b    = (const float*)d_in[9];
  const float* fc2_w    = (const float*)d_in[10];
  const float* fc2_b    = (const float*)d_in[11];
  float* out = (float*)d_out;

  char* p = (char*)d_ws;
  auto alloc = [&](size_t bytes) { char* r = p; p += (bytes + 255) & ~(size_t)255; return r; };
  unsigned short* h0_bf      = (unsigned short*)alloc((size_t)HN * 2);
  unsigned short* h1_bf      = (unsigned short*)alloc((size_t)HN * 2);
  unsigned short* t_bf       = (unsigned short*)alloc((size_t)N_NODES * TDIM * 2);
  unsigned short* wt         = (unsigned short*)alloc((size_t)3 * 128 * TDIM * 2);
  int*            gs         = (int*)alloc((size_t)(N_GRAPHS + 1) * 4);
  int*            row_start  = (int*)alloc((size_t)(N_NODES + 1) * 4);
  int*            ghist      = (int*)alloc((size_t)SCAN_TOT * 4);          // ~230 KB
  int*            spart      = (int*)alloc((size_t)SC2_NB * 4);
  int*            bucket_base= (int*)alloc((size_t)(NCOARSE + 1) * 4);
  int2*           tmp_se     = (int2*)alloc((size_t)N_EDGES * 8);          // 4.8 MB
  int2*           sorted_se  = (int2*)alloc((size_t)(N_EDGES + 8) * 8);

  const int pre_blocks = PRE_ATOM_NB + PRE_CNT_NB + PRE_WCONV_NB + PRE_GB_NB;
  k_pre<<<pre_blocks, 384, 0, stream>>>(x, atom_emb, h0_bf, ei, ghist, W, wt, batch, gs);
  k_gscan_a<<<SC2_NB, 256, 0, stream>>>(ghist, spart);
  k_gscan_b<<<1, 256, 0, stream>>>(spart, bucket_base, row_start);
  k_gscan_c<<<SC2_NB, 256, 0, stream>>>(ghist, spart, bucket_base);
  k_coarse<<<NBLKA, 256, 0, stream>>>(ei, ea, ghist, tmp_se);
  k_fine<<<NCOARSE, 256, 0, stream>>>(tmp_se, bucket_base, row_start, sorted_se);

  unsigned short* hib = h0_bf;
  unsigned short* hob = h1_bf;
  const int gemm_blocks = (N_NODES + GROWS - 1) / GROWS;  // 782
  for (int layer = 0; layer < 3; ++layer) {
    k_agg<<<N_NODES / 16, 256, 0, stream>>>(sorted_se, row_start, bond_emb + layer * 72,
                                            hib, t_bf);
    k_gemm<<<gemm_blocks, 512, 0, stream>>>(
        t_bf, wt + (size_t)layer * 128 * TDIM, b + layer * 3 * EMB,
        hib, hob, layer < 2 ? 1 : 0);
    unsigned short* tb = hib; hib = hob; hob = tb;
  }
  // final h is in hib (h1_bf after 3 swaps)

  k_head<<<N_GRAPHS, 128, 0, stream>>>(hib, gs, fc1_w, fc1_b, fc2_w, fc2_b, out);
}

// Round 12
// 304.169 us; speedup vs baseline: 1.1778x; 1.0360x over previous
//
#include <hip/hip_runtime.h>

#define N_NODES 50000
#define N_EDGES 600000
#define N_GRAPHS 2048
#define EMB 128
#define TDIM 384
#define TS_LD 392               // padded LDS row stride (shorts): 2-way bank alias only
#define HN (N_NODES * EMB)
#define GROWS 64                // k_gemm rows per block

// bucket-sort CSR build (atomic-free)
#define EPB 2048                               // edges per count/scatter block
#define NBLKA ((N_EDGES + EPB - 1) / EPB)      // 293
#define NCOARSE ((N_NODES + 255) / 256)        // 196 coarse buckets (dst>>8)
#define SCAN_TOT (NCOARSE * NBLKA)             // 57428 flat counters
#define SC2_NB ((SCAN_TOT + 255) / 256)        // 225

// prepass block ranges (384 threads/block)
#define PRE_CNT_NB NBLKA        // coarse-digit hist blocks
#define PRE_WCONV_NB 384        // one (layer,col) per block
#define PRE_GB_NB 131           // ceil(50000/384)

// atom-encoder filler ranges (256 threads/block, 4 nodes/block):
// split across k_coarse and k_fine so its latency-bound work (11% HBM, 20% VALU)
// overlaps the BW-bound sort passes instead of serializing ahead of them.
#define ATOM_HALF 25000
#define ATOM_NB 6250            // 25000 / 4

typedef __attribute__((ext_vector_type(8))) short bf16x8;
typedef __attribute__((ext_vector_type(4))) float f32x4;
#define MFMA_BF16(a, b, c) __builtin_amdgcn_mfma_f32_16x16x32_bf16(a, b, c, 0, 0, 0)

#define AS1 __attribute__((address_space(1)))
#define AS3 __attribute__((address_space(3)))
__device__ inline void gl_lds16(const void* g, void* l) {
  // async global->LDS, 16B/lane: LDS dest = l + lane*16 (wave-uniform base), no dest VGPRs
  __builtin_amdgcn_global_load_lds((const AS1 void*)g, (AS3 void*)l, 16, 0, 0);
}

__device__ inline unsigned short f2bf(float f) {
  unsigned int u = __float_as_uint(f);
  u += 0x7fffu + ((u >> 16) & 1u);   // round to nearest even
  return (unsigned short)(u >> 16);
}
__device__ inline float bf2f(unsigned short b) {
  return __uint_as_float(((unsigned int)b) << 16);
}
__device__ inline bf16x8 pack8(float4 lo, float4 hi) {
  bf16x8 r;
  r[0] = (short)f2bf(lo.x); r[1] = (short)f2bf(lo.y);
  r[2] = (short)f2bf(lo.z); r[3] = (short)f2bf(lo.w);
  r[4] = (short)f2bf(hi.x); r[5] = (short)f2bf(hi.y);
  r[6] = (short)f2bf(hi.z); r[7] = (short)f2bf(hi.w);
  return r;
}

// Atom-encoder body: one wave per node (4 waves / 256-thr block), async LDS gathers.
// sb must provide 4*1280 floats (20 KB). Bitwise identical to prior rounds' k_pre path.
__device__ inline void atom_block(int nbase, int blk, const int* __restrict__ x,
                                  const float* __restrict__ atom_emb,
                                  unsigned short* __restrict__ h_bf, float* sb) {
  const int wv = threadIdx.x >> 6;
  const int lane = threadIdx.x & 63;
  int n = nbase + blk * 4 + wv;
  if (n < N_NODES) {
    const int nu = __builtin_amdgcn_readfirstlane(n);
    const int* xr = x + nu * 9;
    int ix[9];
#pragma unroll
    for (int c = 0; c < 9; ++c) ix[c] = xr[c];   // wave-uniform -> s_loads
    float* wbase = sb + wv * 1280;
    const int half = lane >> 5;       // 0: lanes 0-31, 1: lanes 32-63
    const int sub16 = lane & 31;      // 16B slot within the row
#pragma unroll
    for (int j = 0; j < 4; ++j) {
      int c = 2 * j + half;
      const float* g = atom_emb + (size_t)(c * 100 + ix[c]) * EMB + sub16 * 4;
      gl_lds16(g, wbase + j * 256);   // row 2j -> +j*1024B, row 2j+1 -> +j*1024B+512B
    }
    {  // row 8: both halves load the same 512B (lanes 32-63 land in scratch tail)
      const float* g = atom_emb + (size_t)(8 * 100 + ix[8]) * EMB + sub16 * 4;
      gl_lds16(g, wbase + 1024);
    }
    asm volatile("s_waitcnt vmcnt(0)" ::: "memory");
    float2 acc = {0.f, 0.f};
#pragma unroll
    for (int c = 0; c < 9; ++c) {     // row c at wbase + c*128 floats
      float2 v = *(const float2*)(wbase + c * 128 + lane * 2);
      acc.x += v.x; acc.y += v.y;
    }
    *(ushort2*)(h_bf + (size_t)nu * EMB + lane * 2) = ushort2{f2bf(acc.x), f2bf(acc.y)};
  }
}

// ---------------- prepass: coarse-hist | W-transpose | graph-bounds (atom moved out) -------
__global__ __launch_bounds__(384) void k_pre(const int* __restrict__ ei,
                                             int* __restrict__ ghist,
                                             const float* __restrict__ W,
                                             unsigned short* __restrict__ wt,
                                             const int* __restrict__ batch,
                                             int* __restrict__ gs) {
  __shared__ int h[256];
  int blk = blockIdx.x;
  if (blk < PRE_CNT_NB) {               // LDS hist of dst>>8
    const int t = threadIdx.x;
    if (t < 256) h[t] = 0;
    __syncthreads();
    const int base = blk * EPB;
#pragma unroll
    for (int k = 0; k < 6; ++k) {       // 6*384 = 2304 covers EPB=2048
      int o = k * 384 + t;
      int e = base + o;
      if (o < EPB && e < N_EDGES) atomicAdd(&h[ei[N_EDGES + e] >> 8], 1);  // LDS atomic
    }
    __syncthreads();
    if (t < NCOARSE) ghist[(size_t)t * NBLKA + blk] = h[t];
    return;
  }
  blk -= PRE_CNT_NB;
  if (blk < PRE_WCONV_NB) {
    int layer = blk >> 7, c = blk & 127, k = threadIdx.x;
    float v = W[(((layer * 3 + (k >> 7)) * 128) + (k & 127)) * 128 + c];
    wt[(size_t)blk * 384 + k] = f2bf(v);
    return;
  }
  blk -= PRE_WCONV_NB;
  {
    int i = blk * 384 + threadIdx.x;
    if (i < N_NODES) {
      int b = batch[i];
      int bp = (i == 0) ? -1 : batch[i - 1];
      for (int g = bp + 1; g <= b; ++g) gs[g] = i;
      if (i == N_NODES - 1) {
        for (int g = b + 1; g <= N_GRAPHS; ++g) gs[g] = N_NODES;
      }
    }
  }
}

// ---------------- bucket-sort CSR build (no global atomics) ----------------
// GRID-WIDE flat exclusive scan of ghist (digit-major, 57428 ints).
__global__ __launch_bounds__(256) void k_gscan_a(int* __restrict__ ghist,
                                                 int* __restrict__ partials) {
  __shared__ int s[256];
  const int t = threadIdx.x;
  const int i = blockIdx.x * 256 + t;
  int v = (i < SCAN_TOT) ? ghist[i] : 0;
  s[t] = v;
  __syncthreads();
  for (int off = 1; off < 256; off <<= 1) {
    int u = (t >= off) ? s[t - off] : 0;
    __syncthreads();
    s[t] += u;
    __syncthreads();
  }
  if (i < SCAN_TOT) ghist[i] = s[t] - v;          // exclusive within block
  if (t == 255) partials[blockIdx.x] = s[255];
}

__global__ __launch_bounds__(256) void k_gscan_b(int* __restrict__ partials,
                                                 int* __restrict__ bucket_base,
                                                 int* __restrict__ row_start) {
  __shared__ int s[256];
  const int t = threadIdx.x;
  int v = (t < SC2_NB) ? partials[t] : 0;
  s[t] = v;
  __syncthreads();
  for (int off = 1; off < 256; off <<= 1) {
    int u = (t >= off) ? s[t - off] : 0;
    __syncthreads();
    s[t] += u;
    __syncthreads();
  }
  if (t < SC2_NB) partials[t] = s[t] - v;         // exclusive block offsets
  if (t == 0) { bucket_base[NCOARSE] = N_EDGES; row_start[N_NODES] = N_EDGES; }
}

__global__ __launch_bounds__(256) void k_gscan_c(int* __restrict__ ghist,
                                                 const int* __restrict__ partials,
                                                 int* __restrict__ bucket_base) {
  const int i = blockIdx.x * 256 + threadIdx.x;
  if (i < SCAN_TOT) {
    int g = ghist[i] + partials[blockIdx.x];      // global exclusive scan value
    ghist[i] = g;
    int d = i / NBLKA;
    if (i - d * NBLKA == 0) bucket_base[d] = g;   // digit boundary
  }
}

// Coarse scatter {dst|eap<<16, src} + ATOM FILLER (nodes [0, 25000)).
__global__ __launch_bounds__(256) void k_coarse(const int* __restrict__ ei,
                                                const int* __restrict__ ea,
                                                const int* __restrict__ ghist,
                                                int2* __restrict__ tmp,
                                                const int* __restrict__ x,
                                                const float* __restrict__ atom_emb,
                                                unsigned short* __restrict__ h_bf) {
  __shared__ float sb[4 * 1280];   // 20 KB: atom waves OR aliased coarse cnt
  if (blockIdx.x >= NBLKA) {
    atom_block(0, blockIdx.x - NBLKA, x, atom_emb, h_bf, sb);
    return;
  }
  int* cnt = (int*)sb;
  const int t = threadIdx.x;
  cnt[t] = 0;
  __syncthreads();
  const int base = blockIdx.x * EPB;
#pragma unroll
  for (int k = 0; k < 8; ++k) {
    int e = base + k * 256 + t;
    if (e < N_EDGES) {
      int dst = ei[N_EDGES + e];
      int d = dst >> 8;
      int r = atomicAdd(&cnt[d], 1);   // LDS atomic: block-local rank in bucket
      int pos = ghist[(size_t)d * NBLKA + blockIdx.x] + r;
      int eap = ea[e * 3 + 0] | (ea[e * 3 + 1] << 3) | (ea[e * 3 + 2] << 6);
      tmp[pos] = int2{dst | (eap << 16), ei[e]};
    }
  }
}

// Fine pass: hist (dst&255), LDS scan -> row_start, scatter into sorted_se {src, eap}.
// + ATOM FILLER (nodes [25000, 50000)).
__global__ __launch_bounds__(256) void k_fine(const int2* __restrict__ tmp,
                                              const int* __restrict__ bucket_base,
                                              int* __restrict__ row_start,
                                              int2* __restrict__ sorted_se,
                                              const int* __restrict__ x,
                                              const float* __restrict__ atom_emb,
                                              unsigned short* __restrict__ h_bf) {
  __shared__ float sb[4 * 1280];   // 20 KB: atom waves OR aliased fine h/s/ex
  if (blockIdx.x >= NCOARSE) {
    atom_block(ATOM_HALF, blockIdx.x - NCOARSE, x, atom_emb, h_bf, sb);
    return;
  }
  int* h = (int*)sb;
  int* s = h + 256;
  int* ex = s + 256;
  const int t = threadIdx.x;
  const int d = blockIdx.x;
  const int b0 = bucket_base[d], b1 = bucket_base[d + 1];
  h[t] = 0;
  __syncthreads();
  for (int i = b0 + t; i < b1; i += 256) atomicAdd(&h[tmp[i].x & 255], 1);
  __syncthreads();
  s[t] = h[t];
  __syncthreads();
  for (int off = 1; off < 256; off <<= 1) {
    int v = (t >= off) ? s[t - off] : 0;
    __syncthreads();
    s[t] += v;
    __syncthreads();
  }
  ex[t] = s[t] - h[t];                 // exclusive offsets within bucket
  int node = d * 256 + t;
  if (node < N_NODES) row_start[node] = b0 + ex[t];
  h[t] = 0;
  __syncthreads();
  for (int i = b0 + t; i < b1; i += 256) {
    int2 r = tmp[i];
    int f = r.x & 255;
    int pos = b0 + ex[f] + atomicAdd(&h[f], 1);   // LDS atomic
    sorted_se[pos] = int2{r.y, (r.x >> 16) & 511};
  }
}

// ---------------- Edge aggregation: QUARTER-WAVE per node, unroll-8, se-PIPELINED ----------------
// Config ledger: bucketing (r6) -8us, unroll-16 (r7) -27us, half-wave (r0) -7us.
// 2-stage pipeline (r11, +5us): next chunk's se[8] prefetched during gathers/FMAs.
__global__ __launch_bounds__(256) void k_agg(const int2* __restrict__ sorted_se,
                                             const int* __restrict__ row_start,
                                             const float* __restrict__ bl,  // bond_emb[layer]: [3][8][3]
                                             const unsigned short* __restrict__ h_bf,
                                             unsigned short* __restrict__ t_bf) {
  __shared__ float4 combo[512];  // 8 KB
  const int node = blockIdx.x * 16 + (threadIdx.x >> 4);  // quarter-wave per node
  const int sub = threadIdx.x & 15;                       // cols sub*8..+7
  const int beg = row_start[node], end = row_start[node + 1];
  int e = beg;
  const int full_end = beg + ((end - beg) & ~7);
  int2 se[8];
  if (e < full_end) {
#pragma unroll
    for (int j = 0; j < 8; ++j) se[j] = sorted_se[e + j];   // prologue, overlaps combo fill
  }
  for (int c = threadIdx.x; c < 512; c += 256) {
    int a0 = c & 7, a1 = (c >> 3) & 7, a2 = (c >> 6) & 7;
    combo[c] = float4{bl[a0 * 3 + 0] + bl[24 + a1 * 3 + 0] + bl[48 + a2 * 3 + 0],
                      bl[a0 * 3 + 1] + bl[24 + a1 * 3 + 1] + bl[48 + a2 * 3 + 1],
                      bl[a0 * 3 + 2] + bl[24 + a1 * 3 + 2] + bl[48 + a2 * 3 + 2], 0.f};
  }
  __syncthreads();
  float4 l0 = {0.f, 0.f, 0.f, 0.f}, h0 = l0;   // channel 0: cols lo/hi
  float4 l1 = l0, h1 = l0;                     // channel 1
  float4 l2 = l0, h2 = l0;                     // channel 2
  while (e < full_end) {                   // fast path: no bounds logic
    bf16x8 u[8];
#pragma unroll
    for (int j = 0; j < 8; ++j)
      u[j] = *(const bf16x8*)(h_bf + (size_t)se[j].x * EMB + sub * 8);
    e += 8;
    int2 se_n[8];
    const bool more = (e < full_end);
    if (more) {
#pragma unroll
      for (int j = 0; j < 8; ++j) se_n[j] = sorted_se[e + j];  // prefetch next chunk
    }
#pragma unroll
    for (int j = 0; j < 8; ++j) {
      float4 w = combo[se[j].y];
      float4 vlo = {bf2f((unsigned short)u[j][0]), bf2f((unsigned short)u[j][1]),
                    bf2f((unsigned short)u[j][2]), bf2f((unsigned short)u[j][3])};
      float4 vhi = {bf2f((unsigned short)u[j][4]), bf2f((unsigned short)u[j][5]),
                    bf2f((unsigned short)u[j][6]), bf2f((unsigned short)u[j][7])};
      l0 += vlo * w.x; h0 += vhi * w.x;
      l1 += vlo * w.y; h1 += vhi * w.y;
      l2 += vlo * w.z; h2 += vhi * w.z;
    }
    if (more) {
#pragma unroll
      for (int j = 0; j < 8; ++j) se[j] = se_n[j];
    }
  }
  if (e < end) {                           // tail chunk: clamped + weight-selected
    int2 st[8];
#pragma unroll
    for (int j = 0; j < 8; ++j) {
      int idx = e + j;
      st[j] = sorted_se[idx < end ? idx : end - 1];
    }
    bf16x8 u[8];
#pragma unroll
    for (int j = 0; j < 8; ++j)
      u[j] = *(const bf16x8*)(h_bf + (size_t)st[j].x * EMB + sub * 8);
#pragma unroll
    for (int j = 0; j < 8; ++j) {
      float4 w = (e + j < end) ? combo[st[j].y] : float4{0.f, 0.f, 0.f, 0.f};
      float4 vlo = {bf2f((unsigned short)u[j][0]), bf2f((unsigned short)u[j][1]),
                    bf2f((unsigned short)u[j][2]), bf2f((unsigned short)u[j][3])};
      float4 vhi = {bf2f((unsigned short)u[j][4]), bf2f((unsigned short)u[j][5]),
                    bf2f((unsigned short)u[j][6]), bf2f((unsigned short)u[j][7])};
      l0 += vlo * w.x; h0 += vhi * w.x;
      l1 += vlo * w.y; h1 += vhi * w.y;
      l2 += vlo * w.z; h2 += vhi * w.z;
    }
  }
  size_t base = (size_t)node * TDIM + sub * 8;
  *(bf16x8*)(t_bf + base)       = pack8(l0, h0);
  *(bf16x8*)(t_bf + base + 128) = pack8(l1, h1);
  *(bf16x8*)(t_bf + base + 256) = pack8(l2, h2);
}

// ---------------- MFMA GEMM: 64-row blocks; B-frags/bias hoisted above staging ----------------
// Block 512 thr = 8 waves; 64 nodes/block; grid 782; LDS 50 KB -> 3 blocks/CU.
// A-frag: A[m=lane&15][k=(lane>>4)*8+j]; B-frag: B[k][n=lane&15];
// C/D: col=lane&15, row=(lane>>4)*4+reg.
__global__ __launch_bounds__(512) void k_gemm(const unsigned short* __restrict__ t_bf,
                                              const unsigned short* __restrict__ wt,  // [128][384]
                                              const float* __restrict__ bl,  // [3][128]
                                              const unsigned short* __restrict__ h_in_bf,
                                              unsigned short* __restrict__ h_out_bf,
                                              int do_relu) {
  __shared__ unsigned short ts[GROWS * TS_LD];   // 50.2 KB
  const int nb = blockIdx.x * GROWS;
  const int wv = threadIdx.x >> 6;
  const int lane = threadIdx.x & 63;
  const int m = lane & 15;
  const int kq = lane >> 4;
  const int c = wv * 16 + m;

  // B-frags + bias issued FIRST: these global loads overlap the staging loop + barrier
  const unsigned short* pB = wt + (size_t)c * TDIM + kq * 8;
  bf16x8 B[12];
#pragma unroll
  for (int kc = 0; kc < 12; ++kc) B[kc] = *(const bf16x8*)(pB + kc * 32);
  const float bias = bl[c] + bl[128 + c] + bl[256 + c];

  for (int i = threadIdx.x; i < GROWS * 48; i += 512) {
    int r = i / 48, cc = i % 48;
    bf16x8 v = {};
    int row = nb + r;
    if (row < N_NODES) v = *(const bf16x8*)(t_bf + (size_t)row * TDIM + cc * 8);
    *(bf16x8*)(ts + r * TS_LD + cc * 8) = v;
  }
  __syncthreads();

#pragma unroll
  for (int rt = 0; rt < 4; ++rt) {
    const unsigned short* pA = ts + (rt * 16 + m) * TS_LD + kq * 8;
    bf16x8 A[12];
#pragma unroll
    for (int kc = 0; kc < 12; ++kc) A[kc] = *(const bf16x8*)(pA + kc * 32);
    f32x4 acc = {0.f, 0.f, 0.f, 0.f};
#pragma unroll
    for (int kc = 0; kc < 12; ++kc) acc = MFMA_BF16(A[kc], B[kc], acc);
#pragma unroll
    for (int r = 0; r < 4; ++r) {
      int row = nb + rt * 16 + kq * 4 + r;
      if (row < N_NODES) {
        size_t idx = (size_t)row * EMB + c;
        float v = acc[r] + bias;
        if (do_relu) v = fmaxf(v, 0.f);
        float hn = bf2f(h_in_bf[idx]) + v;
        h_out_bf[idx] = f2bf(hn);
      }
    }
  }
}

// ---------------- fused mean-pool + head: block g reduces its contiguous node range ----------------
__global__ __launch_bounds__(128) void k_head(const unsigned short* __restrict__ h_bf,
                                              const int* __restrict__ gs,
                                              const float* __restrict__ fc1_w,
                                              const float* __restrict__ fc1_b,
                                              const float* __restrict__ fc2_w,
                                              const float* __restrict__ fc2_b,
                                              float* __restrict__ out) {
  __shared__ float hg[EMB];
  __shared__ float red[EMB];
  int g = blockIdx.x, e = threadIdx.x;
  int ns = gs[g], ne = gs[g + 1];
  float acc = 0.f;
  for (int n = ns; n < ne; ++n) acc += bf2f(h_bf[(size_t)n * EMB + e]);
  float cnt = fmaxf((float)(ne - ns), 1.f);
  hg[e] = acc / cnt;
  __syncthreads();
  float a2 = fc1_b[e];
  for (int j = 0; j < EMB; ++j) a2 += hg[j] * fc1_w[j * EMB + e];
  red[e] = a2 * fc2_w[e];
  __syncthreads();
  for (int s = 64; s > 0; s >>= 1) {
    if (e < s) red[e] += red[e + s];
    __syncthreads();
  }
  if (e == 0) out[g] = red[0] + fc2_b[0];
}

extern "C" void kernel_launch(void* const* d_in, const int* in_sizes, int n_in,
                              void* d_out, int out_size, void* d_ws, size_t ws_size,
                              hipStream_t stream) {
  const int*   x        = (const int*)d_in[0];
  const int*   ei       = (const int*)d_in[1];
  const int*   ea       = (const int*)d_in[2];
  const int*   batch    = (const int*)d_in[3];
  const float* atom_emb = (const float*)d_in[4];
  const float* bond_emb = (const float*)d_in[5];
  const float* W        = (const float*)d_in[6];
  const float* b        = (const float*)d_in[7];
  const float* fc1_w    = (const float*)d_in[8];
  const float* fc1_b    = (const float*)d_in[9];
  const float* fc2_w    = (const float*)d_in[10];
  const float* fc2_b    = (const float*)d_in[11];
  float* out = (float*)d_out;

  char* p = (char*)d_ws;
  auto alloc = [&](size_t bytes) { char* r = p; p += (bytes + 255) & ~(size_t)255; return r; };
  unsigned short* h0_bf      = (unsigned short*)alloc((size_t)HN * 2);
  unsigned short* h1_bf      = (unsigned short*)alloc((size_t)HN * 2);
  unsigned short* t_bf       = (unsigned short*)alloc((size_t)N_NODES * TDIM * 2);
  unsigned short* wt         = (unsigned short*)alloc((size_t)3 * 128 * TDIM * 2);
  int*            gs         = (int*)alloc((size_t)(N_GRAPHS + 1) * 4);
  int*            row_start  = (int*)alloc((size_t)(N_NODES + 1) * 4);
  int*            ghist      = (int*)alloc((size_t)SCAN_TOT * 4);          // ~230 KB
  int*            spart      = (int*)alloc((size_t)SC2_NB * 4);
  int*            bucket_base= (int*)alloc((size_t)(NCOARSE + 1) * 4);
  int2*           tmp_se     = (int2*)alloc((size_t)N_EDGES * 8);          // 4.8 MB
  int2*           sorted_se  = (int2*)alloc((size_t)(N_EDGES + 8) * 8);

  const int pre_blocks = PRE_CNT_NB + PRE_WCONV_NB + PRE_GB_NB;
  k_pre<<<pre_blocks, 384, 0, stream>>>(ei, ghist, W, wt, batch, gs);
  k_gscan_a<<<SC2_NB, 256, 0, stream>>>(ghist, spart);
  k_gscan_b<<<1, 256, 0, stream>>>(spart, bucket_base, row_start);
  k_gscan_c<<<SC2_NB, 256, 0, stream>>>(ghist, spart, bucket_base);
  k_coarse<<<NBLKA + ATOM_NB, 256, 0, stream>>>(ei, ea, ghist, tmp_se,
                                                x, atom_emb, h0_bf);
  k_fine<<<NCOARSE + ATOM_NB, 256, 0, stream>>>(tmp_se, bucket_base, row_start, sorted_se,
                                                x, atom_emb, h0_bf);

  unsigned short* hib = h0_bf;
  unsigned short* hob = h1_bf;
  const int gemm_blocks = (N_NODES + GROWS - 1) / GROWS;  // 782
  for (int layer = 0; layer < 3; ++layer) {
    k_agg<<<N_NODES / 16, 256, 0, stream>>>(sorted_se, row_start, bond_emb + layer * 72,
                                            hib, t_bf);
    k_gemm<<<gemm_blocks, 512, 0, stream>>>(
        t_bf, wt + (size_t)layer * 128 * TDIM, b + layer * 3 * EMB,
        hib, hob, layer < 2 ? 1 : 0);
    unsigned short* tb = hib; hib = hob; hob = tb;
  }
  // final h is in hib (h1_bf after 3 swaps)

  k_head<<<N_GRAPHS, 128, 0, stream>>>(hib, gs, fc1_w, fc1_b, fc2_w, fc2_b, out);
}